// Round 1
// baseline (637.805 us; speedup 1.0000x reference)
//
#include <hip/hip_runtime.h>
#include <hip/hip_bf16.h>

#define H_    2048
#define NROWS 16384
#define HH    1024

typedef __bf16 bf16x8 __attribute__((ext_vector_type(8)));
typedef float  floatx4 __attribute__((ext_vector_type(4)));

__device__ __forceinline__ unsigned short f2bf(float f) {
  unsigned u = __builtin_bit_cast(unsigned, f);
  u += 0x7fff + ((u >> 16) & 1);          // round-nearest-even to bf16
  return (unsigned short)(u >> 16);
}

// ---------------------------------------------------------------------------
// K1: h = relu(x @ W_e1 + b_e1); s_pre[row] += h_tile . W_e2_tile  (fused)
// 128x128 output tile per block, K=2048 in chunks of 32, bf16 MFMA 16x16x32.
// ---------------------------------------------------------------------------
__global__ __launch_bounds__(256) void gemm_score_kernel(
    const float* __restrict__ x, const float* __restrict__ W1,
    const float* __restrict__ b1, const float* __restrict__ W2,
    float* __restrict__ s_pre)
{
  __shared__ unsigned short As[128][40];   // [m][k], pad 32->40 (80B rows, 16B-aligned frags)
  __shared__ unsigned short Bs[128][40];   // [n][k] (transposed W1 tile)

  const int t    = threadIdx.x;
  const int n0   = blockIdx.x * 128;       // hidden-col tile (fast dim -> A reuse in L2)
  const int m0   = blockIdx.y * 128;       // row tile
  const int wave = t >> 6, lane = t & 63;
  const int wr   = (wave >> 1) * 64;       // wave row offset within tile
  const int wc   = (wave & 1) * 64;        // wave col offset
  const int lcol = lane & 15, quad = lane >> 4;

  floatx4 acc[4][4] = {};

  for (int kk = 0; kk < H_; kk += 32) {
    __syncthreads();
    // stage A: 128 rows x 32 k of x (fp32) -> bf16 LDS
#pragma unroll
    for (int i = 0; i < 4; i++) {
      int idx = t + i * 256;
      int row = idx >> 3, k4 = (idx & 7) << 2;
      float4 v = *reinterpret_cast<const float4*>(x + (size_t)(m0 + row) * H_ + kk + k4);
      unsigned lo = (unsigned)f2bf(v.x) | ((unsigned)f2bf(v.y) << 16);
      unsigned hi = (unsigned)f2bf(v.z) | ((unsigned)f2bf(v.w) << 16);
      *reinterpret_cast<uint2*>(&As[row][k4]) = make_uint2(lo, hi);
    }
    // stage B: W1 rows kk..kk+31, cols n0..n0+127 -> transposed Bs[n][k]
#pragma unroll
    for (int i = 0; i < 4; i++) {
      int idx = t + i * 256;
      int kr = idx >> 5, c4 = (idx & 31) << 2;
      float4 v = *reinterpret_cast<const float4*>(W1 + (size_t)(kk + kr) * HH + n0 + c4);
      Bs[c4 + 0][kr] = f2bf(v.x);
      Bs[c4 + 1][kr] = f2bf(v.y);
      Bs[c4 + 2][kr] = f2bf(v.z);
      Bs[c4 + 3][kr] = f2bf(v.w);
    }
    __syncthreads();

    bf16x8 af[4], bfr[4];
#pragma unroll
    for (int mt = 0; mt < 4; mt++)
      af[mt] = *reinterpret_cast<const bf16x8*>(&As[wr + mt * 16 + lcol][quad * 8]);
#pragma unroll
    for (int nt = 0; nt < 4; nt++)
      bfr[nt] = *reinterpret_cast<const bf16x8*>(&Bs[wc + nt * 16 + lcol][quad * 8]);
#pragma unroll
    for (int mt = 0; mt < 4; mt++)
#pragma unroll
      for (int nt = 0; nt < 4; nt++)
        acc[mt][nt] = __builtin_amdgcn_mfma_f32_16x16x32_bf16(af[mt], bfr[nt], acc[mt][nt], 0, 0, 0);
  }

  // epilogue: relu(acc + b1[n]) * W2[n], summed over this block's 128 n-cols
  float rowsum[4][4];
#pragma unroll
  for (int mt = 0; mt < 4; mt++)
#pragma unroll
    for (int r = 0; r < 4; r++) rowsum[mt][r] = 0.f;

#pragma unroll
  for (int nt = 0; nt < 4; nt++) {
    int n = n0 + wc + nt * 16 + lcol;     // C/D col = lane&15
    float b1v = b1[n], w2v = W2[n];
#pragma unroll
    for (int mt = 0; mt < 4; mt++)
#pragma unroll
      for (int r = 0; r < 4; r++) {
        float h = acc[mt][nt][r] + b1v;
        h = fmaxf(h, 0.f);
        rowsum[mt][r] = fmaf(h, w2v, rowsum[mt][r]);
      }
  }
#pragma unroll
  for (int mt = 0; mt < 4; mt++)
#pragma unroll
    for (int r = 0; r < 4; r++) {
      float s = rowsum[mt][r];
      s += __shfl_xor(s, 1); s += __shfl_xor(s, 2);
      s += __shfl_xor(s, 4); s += __shfl_xor(s, 8);
      if (lcol == 0)
        atomicAdd(&s_pre[m0 + wr + mt * 16 + quad * 4 + r], s);  // C/D row = quad*4+r
    }
}

// ---------------------------------------------------------------------------
// K2: sigmoid/threshold, per-row softmax weight (exp(importance) masked),
//     global sum Z and event count.
// ---------------------------------------------------------------------------
__global__ __launch_bounds__(256) void score_kernel(
    const float* __restrict__ s_pre, const float* __restrict__ imp,
    const float* __restrict__ b2, float* __restrict__ wbuf,
    float* __restrict__ Z, float* __restrict__ cnt)
{
  int i = blockIdx.x * 256 + threadIdx.x;
  float s = s_pre[i] + b2[0];
  float sig = 1.f / (1.f + __expf(-s));
  bool ev = sig > 0.7f;
  float w = ev ? __expf(imp[i]) : 0.f;
  wbuf[i] = w;
  float cw = ev ? 1.f : 0.f;
#pragma unroll
  for (int off = 32; off; off >>= 1) {
    w  += __shfl_down(w, off);
    cw += __shfl_down(cw, off);
  }
  if ((threadIdx.x & 63) == 0) {
    atomicAdd(Z, w);
    atomicAdd(cnt, cw);
  }
}

// ---------------------------------------------------------------------------
// K3: c[j] = sum_i wbuf[i] * x[i][j]   (unnormalized consolidated)
// ---------------------------------------------------------------------------
__global__ __launch_bounds__(256) void consolidate_kernel(
    const float* __restrict__ x, const float* __restrict__ wbuf,
    float* __restrict__ c)
{
  int t = threadIdx.x;
  int r0 = blockIdx.x * 128;
  float a[8] = {0.f, 0.f, 0.f, 0.f, 0.f, 0.f, 0.f, 0.f};
  for (int r = 0; r < 128; r++) {
    float w = wbuf[r0 + r];                // uniform across block -> no divergence
    if (w != 0.f) {
      const float4* xr = reinterpret_cast<const float4*>(x + (size_t)(r0 + r) * H_);
      float4 v0 = xr[t], v1 = xr[t + 256];
      a[0] = fmaf(w, v0.x, a[0]); a[1] = fmaf(w, v0.y, a[1]);
      a[2] = fmaf(w, v0.z, a[2]); a[3] = fmaf(w, v0.w, a[3]);
      a[4] = fmaf(w, v1.x, a[4]); a[5] = fmaf(w, v1.y, a[5]);
      a[6] = fmaf(w, v1.z, a[6]); a[7] = fmaf(w, v1.w, a[7]);
    }
  }
  int j0 = t * 4;
  atomicAdd(&c[j0 + 0], a[0]); atomicAdd(&c[j0 + 1], a[1]);
  atomicAdd(&c[j0 + 2], a[2]); atomicAdd(&c[j0 + 3], a[3]);
  atomicAdd(&c[1024 + j0 + 0], a[4]); atomicAdd(&c[1024 + j0 + 1], a[5]);
  atomicAdd(&c[1024 + j0 + 2], a[6]); atomicAdd(&c[1024 + j0 + 3], a[7]);
}

// ---------------------------------------------------------------------------
// K4: hr_pre[n] += (c/Z) . W_r1[:,n]   (split-K GEMV)
// ---------------------------------------------------------------------------
__global__ __launch_bounds__(256) void r1_kernel(
    const float* __restrict__ c, const float* __restrict__ Z,
    const float* __restrict__ cnt, const float* __restrict__ Wr1,
    float* __restrict__ hr)
{
  __shared__ float cs[128];
  int n  = blockIdx.x * 256 + threadIdx.x;   // 4 blocks -> 1024
  int k0 = blockIdx.y * 128;                 // 16 k-chunks
  float inv = (cnt[0] > 0.5f) ? (1.f / Z[0]) : 0.f;
  if (threadIdx.x < 128) cs[threadIdx.x] = c[k0 + threadIdx.x] * inv;
  __syncthreads();
  float s = 0.f;
#pragma unroll 8
  for (int k = 0; k < 128; k++)
    s = fmaf(cs[k], Wr1[(size_t)(k0 + k) * HH + n], s);
  atomicAdd(&hr[n], s);
}

// ---------------------------------------------------------------------------
// K5: rt_pre[n] += relu(hr_pre + b_r1) . W_r2[:,n]   (split-K GEMV)
// ---------------------------------------------------------------------------
__global__ __launch_bounds__(256) void r2_kernel(
    const float* __restrict__ hr, const float* __restrict__ br1,
    const float* __restrict__ Wr2, float* __restrict__ rt)
{
  __shared__ float hs[128];
  int n  = blockIdx.x * 256 + threadIdx.x;   // 8 blocks -> 2048
  int k0 = blockIdx.y * 128;                 // 8 k-chunks
  if (threadIdx.x < 128)
    hs[threadIdx.x] = fmaxf(hr[k0 + threadIdx.x] + br1[k0 + threadIdx.x], 0.f);
  __syncthreads();
  float s = 0.f;
#pragma unroll 8
  for (int k = 0; k < 128; k++)
    s = fmaf(hs[k], Wr2[(size_t)(k0 + k) * H_ + n], s);
  atomicAdd(&rt[n], s);
}

// ---------------------------------------------------------------------------
// K6: add[j] = has_events ? sigmoid(rt_pre[j] + b_r2[j]) : 0
// ---------------------------------------------------------------------------
__global__ __launch_bounds__(256) void finalize_kernel(
    const float* __restrict__ rt, const float* __restrict__ br2,
    const float* __restrict__ cnt, float* __restrict__ addv)
{
  int j = blockIdx.x * 256 + threadIdx.x;
  float v = 0.f;
  if (cnt[0] > 0.5f) v = 1.f / (1.f + expf(-(rt[j] + br2[j])));
  addv[j] = v;
}

// ---------------------------------------------------------------------------
// K7: out = x + add (broadcast over rows), float4
// ---------------------------------------------------------------------------
__global__ __launch_bounds__(256) void out_kernel(
    const float* __restrict__ x, const float* __restrict__ addv,
    float* __restrict__ out)
{
  size_t i = (size_t)blockIdx.x * 256 + threadIdx.x;   // float4 index
  int j4 = (int)(i & 511);
  float4 a = reinterpret_cast<const float4*>(addv)[j4];
  float4 v = reinterpret_cast<const float4*>(x)[i];
  v.x += a.x; v.y += a.y; v.z += a.z; v.w += a.w;
  reinterpret_cast<float4*>(out)[i] = v;
}

// ---------------------------------------------------------------------------
extern "C" void kernel_launch(void* const* d_in, const int* in_sizes, int n_in,
                              void* d_out, int out_size, void* d_ws, size_t ws_size,
                              hipStream_t stream)
{
  (void)in_sizes; (void)n_in; (void)out_size; (void)ws_size;
  const float* x   = (const float*)d_in[0];
  const float* imp = (const float*)d_in[1];
  const float* We1 = (const float*)d_in[2];
  const float* be1 = (const float*)d_in[3];
  const float* We2 = (const float*)d_in[4];
  const float* be2 = (const float*)d_in[5];
  const float* Wr1 = (const float*)d_in[6];
  const float* br1 = (const float*)d_in[7];
  const float* Wr2 = (const float*)d_in[8];
  const float* br2 = (const float*)d_in[9];
  float* out = (float*)d_out;

  float* ws    = (float*)d_ws;
  float* s_pre = ws;            // 16384
  float* c     = ws + 16384;    // 2048
  float* hr    = ws + 18432;    // 1024
  float* rt    = ws + 19456;    // 2048
  float* Z     = ws + 21504;    // 1
  float* cnt   = ws + 21505;    // 1
  float* wbuf  = ws + 21760;    // 16384 (no init needed, fully written)
  float* addv  = ws + 38144;    // 2048  (no init needed, fully written)

  hipMemsetAsync(d_ws, 0, 21506 * sizeof(float), stream);   // zero atomic targets

  gemm_score_kernel<<<dim3(8, 128), 256, 0, stream>>>(x, We1, be1, We2, s_pre);
  score_kernel<<<64, 256, 0, stream>>>(s_pre, imp, be2, wbuf, Z, cnt);
  consolidate_kernel<<<128, 256, 0, stream>>>(x, wbuf, c);
  r1_kernel<<<dim3(4, 16), 256, 0, stream>>>(c, Z, cnt, Wr1, hr);
  r2_kernel<<<dim3(8, 8), 256, 0, stream>>>(hr, br1, Wr2, rt);
  finalize_kernel<<<8, 256, 0, stream>>>(rt, br2, cnt, addv);
  out_kernel<<<32768, 256, 0, stream>>>(x, addv, out);
}

// Round 2
// 467.804 us; speedup vs baseline: 1.3634x; 1.3634x over previous
//
#include <hip/hip_runtime.h>
#include <hip/hip_bf16.h>

#define H_    2048
#define NROWS 16384
#define HH    1024

typedef __bf16 bf16x8 __attribute__((ext_vector_type(8)));
typedef float  floatx4 __attribute__((ext_vector_type(4)));

__device__ __forceinline__ unsigned f2bf(float f) {
  unsigned u = __builtin_bit_cast(unsigned, f);
  u += 0x7fff + ((u >> 16) & 1);          // round-nearest-even to bf16
  return u >> 16;
}

__device__ __forceinline__ void gload_lds16(const void* g, void* l) {
  // 16B per lane, lands at wave-uniform LDS base + lane*16
  __builtin_amdgcn_global_load_lds(
      (const __attribute__((address_space(1))) unsigned*)g,
      (__attribute__((address_space(3))) unsigned*)l, 16, 0, 0);
}

// ---------------------------------------------------------------------------
// Kc: x fp32 -> xb bf16 (row-major, same layout). 8 elems/thread.
// ---------------------------------------------------------------------------
__global__ __launch_bounds__(256) void convert_x_kernel(
    const float* __restrict__ x, unsigned short* __restrict__ xb)
{
  size_t i = ((size_t)blockIdx.x * 256 + threadIdx.x) * 8;
  float4 v0 = *reinterpret_cast<const float4*>(x + i);
  float4 v1 = *reinterpret_cast<const float4*>(x + i + 4);
  uint4 o;
  o.x = f2bf(v0.x) | (f2bf(v0.y) << 16);
  o.y = f2bf(v0.z) | (f2bf(v0.w) << 16);
  o.z = f2bf(v1.x) | (f2bf(v1.y) << 16);
  o.w = f2bf(v1.z) | (f2bf(v1.w) << 16);
  *reinterpret_cast<uint4*>(xb + i) = o;
}

// ---------------------------------------------------------------------------
// Kt: W1 [k=2048][n=1024] fp32 -> W1t [n][k] bf16 via LDS tile transpose.
// ---------------------------------------------------------------------------
__global__ __launch_bounds__(256) void transpose_w1_kernel(
    const float* __restrict__ W1, unsigned short* __restrict__ W1t)
{
  __shared__ unsigned short tile[64][66];   // [k][n], pad 66 -> conflict-free col reads
  int k0 = blockIdx.x * 64;                 // 32
  int n0 = blockIdx.y * 64;                 // 16
  int t = threadIdx.x;
#pragma unroll
  for (int i = 0; i < 4; i++) {
    int idx = t + i * 256;
    int r = idx >> 4, c4 = (idx & 15) << 2;
    float4 v = *reinterpret_cast<const float4*>(W1 + (size_t)(k0 + r) * HH + n0 + c4);
    tile[r][c4 + 0] = (unsigned short)f2bf(v.x);
    tile[r][c4 + 1] = (unsigned short)f2bf(v.y);
    tile[r][c4 + 2] = (unsigned short)f2bf(v.z);
    tile[r][c4 + 3] = (unsigned short)f2bf(v.w);
  }
  __syncthreads();
#pragma unroll
  for (int i = 0; i < 2; i++) {
    int idx = t + i * 256;
    int n = idx >> 3, k8 = (idx & 7) << 3;
    uint4 o;
    o.x = (unsigned)tile[k8 + 0][n] | ((unsigned)tile[k8 + 1][n] << 16);
    o.y = (unsigned)tile[k8 + 2][n] | ((unsigned)tile[k8 + 3][n] << 16);
    o.z = (unsigned)tile[k8 + 4][n] | ((unsigned)tile[k8 + 5][n] << 16);
    o.w = (unsigned)tile[k8 + 6][n] | ((unsigned)tile[k8 + 7][n] << 16);
    *reinterpret_cast<uint4*>(W1t + (size_t)(n0 + n) * H_ + k0 + k8) = o;
  }
}

// ---------------------------------------------------------------------------
// K1 (fast): m97-style bf16 MFMA GEMM, 128x128 tile, BK=32, global_load_lds,
// fused relu(+b1)*W2 row-reduction epilogue -> s_pre.
// ---------------------------------------------------------------------------
__global__ __launch_bounds__(256) void gemm_v2_kernel(
    const unsigned short* __restrict__ xb, const unsigned short* __restrict__ W1t,
    const float* __restrict__ b1, const float* __restrict__ W2,
    float* __restrict__ s_pre)
{
  __shared__ unsigned short As[128 * 32];   // [m][k], unpadded (global_load_lds order)
  __shared__ unsigned short Bs[128 * 32];   // [n][k]

  const int t    = threadIdx.x;
  const int n0   = blockIdx.x * 128;
  const int m0   = blockIdx.y * 128;
  const int wave = t >> 6, lane = t & 63;
  const int wr   = (wave >> 1) * 64;
  const int wc   = (wave & 1) * 64;
  const int lcol = lane & 15, quad = lane >> 4;

  floatx4 acc[4][4] = {};

  // staging addresses: chunk g = j*256 + t ; row = g>>2 ; k-off = (g&3)*8
  const unsigned short* ag0 = xb  + (size_t)(m0 + (t >> 2)) * H_ + (t & 3) * 8;
  const unsigned short* ag1 = ag0 + (size_t)64 * H_;
  const unsigned short* bg0 = W1t + (size_t)(n0 + (t >> 2)) * H_ + (t & 3) * 8;
  const unsigned short* bg1 = bg0 + (size_t)64 * H_;
  unsigned short* al0 = As + 512 * wave;          // + lane*16B by HW
  unsigned short* al1 = As + 2048 + 512 * wave;
  unsigned short* bl0 = Bs + 512 * wave;
  unsigned short* bl1 = Bs + 2048 + 512 * wave;

  for (int kk = 0; kk < H_; kk += 32) {
    __syncthreads();
    gload_lds16(ag0 + kk, al0);
    gload_lds16(ag1 + kk, al1);
    gload_lds16(bg0 + kk, bl0);
    gload_lds16(bg1 + kk, bl1);
    __syncthreads();

    bf16x8 af[4], bfr[4];
#pragma unroll
    for (int mt = 0; mt < 4; mt++)
      af[mt] = *reinterpret_cast<const bf16x8*>(As + (wr + mt * 16 + lcol) * 32 + quad * 8);
#pragma unroll
    for (int nt = 0; nt < 4; nt++)
      bfr[nt] = *reinterpret_cast<const bf16x8*>(Bs + (wc + nt * 16 + lcol) * 32 + quad * 8);
#pragma unroll
    for (int mt = 0; mt < 4; mt++)
#pragma unroll
      for (int nt = 0; nt < 4; nt++)
        acc[mt][nt] = __builtin_amdgcn_mfma_f32_16x16x32_bf16(af[mt], bfr[nt], acc[mt][nt], 0, 0, 0);
  }

  // epilogue: relu(acc + b1[n]) * W2[n] summed over this block's 128 n-cols
  float rowsum[4][4];
#pragma unroll
  for (int mt = 0; mt < 4; mt++)
#pragma unroll
    for (int r = 0; r < 4; r++) rowsum[mt][r] = 0.f;

#pragma unroll
  for (int nt = 0; nt < 4; nt++) {
    int n = n0 + wc + nt * 16 + lcol;      // C/D col = lane&15
    float b1v = b1[n], w2v = W2[n];
#pragma unroll
    for (int mt = 0; mt < 4; mt++)
#pragma unroll
      for (int r = 0; r < 4; r++) {
        float h = fmaxf(acc[mt][nt][r] + b1v, 0.f);
        rowsum[mt][r] = fmaf(h, w2v, rowsum[mt][r]);
      }
  }
#pragma unroll
  for (int mt = 0; mt < 4; mt++)
#pragma unroll
    for (int r = 0; r < 4; r++) {
      float s = rowsum[mt][r];
      s += __shfl_xor(s, 1); s += __shfl_xor(s, 2);
      s += __shfl_xor(s, 4); s += __shfl_xor(s, 8);
      if (lcol == 0)
        atomicAdd(&s_pre[m0 + wr + mt * 16 + quad * 4 + r], s);  // C/D row = quad*4+r
    }
}

// ---------------------------------------------------------------------------
// K1 (fallback, small ws): round-1 fused GEMM with in-loop conversion.
// ---------------------------------------------------------------------------
__global__ __launch_bounds__(256) void gemm_score_kernel(
    const float* __restrict__ x, const float* __restrict__ W1,
    const float* __restrict__ b1, const float* __restrict__ W2,
    float* __restrict__ s_pre)
{
  __shared__ unsigned short As[128][40];
  __shared__ unsigned short Bs[128][40];
  const int t    = threadIdx.x;
  const int n0   = blockIdx.x * 128;
  const int m0   = blockIdx.y * 128;
  const int wave = t >> 6, lane = t & 63;
  const int wr   = (wave >> 1) * 64;
  const int wc   = (wave & 1) * 64;
  const int lcol = lane & 15, quad = lane >> 4;
  floatx4 acc[4][4] = {};

  for (int kk = 0; kk < H_; kk += 32) {
    __syncthreads();
#pragma unroll
    for (int i = 0; i < 4; i++) {
      int idx = t + i * 256;
      int row = idx >> 3, k4 = (idx & 7) << 2;
      float4 v = *reinterpret_cast<const float4*>(x + (size_t)(m0 + row) * H_ + kk + k4);
      unsigned lo = f2bf(v.x) | (f2bf(v.y) << 16);
      unsigned hi = f2bf(v.z) | (f2bf(v.w) << 16);
      *reinterpret_cast<uint2*>(&As[row][k4]) = make_uint2(lo, hi);
    }
#pragma unroll
    for (int i = 0; i < 4; i++) {
      int idx = t + i * 256;
      int kr = idx >> 5, c4 = (idx & 31) << 2;
      float4 v = *reinterpret_cast<const float4*>(W1 + (size_t)(kk + kr) * HH + n0 + c4);
      Bs[c4 + 0][kr] = (unsigned short)f2bf(v.x);
      Bs[c4 + 1][kr] = (unsigned short)f2bf(v.y);
      Bs[c4 + 2][kr] = (unsigned short)f2bf(v.z);
      Bs[c4 + 3][kr] = (unsigned short)f2bf(v.w);
    }
    __syncthreads();
    bf16x8 af[4], bfr[4];
#pragma unroll
    for (int mt = 0; mt < 4; mt++)
      af[mt] = *reinterpret_cast<const bf16x8*>(&As[wr + mt * 16 + lcol][quad * 8]);
#pragma unroll
    for (int nt = 0; nt < 4; nt++)
      bfr[nt] = *reinterpret_cast<const bf16x8*>(&Bs[wc + nt * 16 + lcol][quad * 8]);
#pragma unroll
    for (int mt = 0; mt < 4; mt++)
#pragma unroll
      for (int nt = 0; nt < 4; nt++)
        acc[mt][nt] = __builtin_amdgcn_mfma_f32_16x16x32_bf16(af[mt], bfr[nt], acc[mt][nt], 0, 0, 0);
  }
  float rowsum[4][4];
#pragma unroll
  for (int mt = 0; mt < 4; mt++)
#pragma unroll
    for (int r = 0; r < 4; r++) rowsum[mt][r] = 0.f;
#pragma unroll
  for (int nt = 0; nt < 4; nt++) {
    int n = n0 + wc + nt * 16 + lcol;
    float b1v = b1[n], w2v = W2[n];
#pragma unroll
    for (int mt = 0; mt < 4; mt++)
#pragma unroll
      for (int r = 0; r < 4; r++) {
        float h = fmaxf(acc[mt][nt][r] + b1v, 0.f);
        rowsum[mt][r] = fmaf(h, w2v, rowsum[mt][r]);
      }
  }
#pragma unroll
  for (int mt = 0; mt < 4; mt++)
#pragma unroll
    for (int r = 0; r < 4; r++) {
      float s = rowsum[mt][r];
      s += __shfl_xor(s, 1); s += __shfl_xor(s, 2);
      s += __shfl_xor(s, 4); s += __shfl_xor(s, 8);
      if (lcol == 0)
        atomicAdd(&s_pre[m0 + wr + mt * 16 + quad * 4 + r], s);
    }
}

// ---------------------------------------------------------------------------
// K2: sigmoid/threshold, masked exp(importance), global Z and event count.
// ---------------------------------------------------------------------------
__global__ __launch_bounds__(256) void score_kernel(
    const float* __restrict__ s_pre, const float* __restrict__ imp,
    const float* __restrict__ b2, float* __restrict__ wbuf,
    float* __restrict__ Z, float* __restrict__ cnt)
{
  int i = blockIdx.x * 256 + threadIdx.x;
  float s = s_pre[i] + b2[0];
  float sig = 1.f / (1.f + __expf(-s));
  bool ev = sig > 0.7f;
  float w = ev ? __expf(imp[i]) : 0.f;
  wbuf[i] = w;
  float cw = ev ? 1.f : 0.f;
#pragma unroll
  for (int off = 32; off; off >>= 1) {
    w  += __shfl_down(w, off);
    cw += __shfl_down(cw, off);
  }
  if ((threadIdx.x & 63) == 0) {
    atomicAdd(Z, w);
    atomicAdd(cnt, cw);
  }
}

// ---------------------------------------------------------------------------
// K3: c[j] = sum_i wbuf[i] * x[i][j]
// ---------------------------------------------------------------------------
__global__ __launch_bounds__(256) void consolidate_kernel(
    const float* __restrict__ x, const float* __restrict__ wbuf,
    float* __restrict__ c)
{
  int t = threadIdx.x;
  int r0 = blockIdx.x * 128;
  float a[8] = {0.f, 0.f, 0.f, 0.f, 0.f, 0.f, 0.f, 0.f};
  for (int r = 0; r < 128; r++) {
    float w = wbuf[r0 + r];
    if (w != 0.f) {
      const float4* xr = reinterpret_cast<const float4*>(x + (size_t)(r0 + r) * H_);
      float4 v0 = xr[t], v1 = xr[t + 256];
      a[0] = fmaf(w, v0.x, a[0]); a[1] = fmaf(w, v0.y, a[1]);
      a[2] = fmaf(w, v0.z, a[2]); a[3] = fmaf(w, v0.w, a[3]);
      a[4] = fmaf(w, v1.x, a[4]); a[5] = fmaf(w, v1.y, a[5]);
      a[6] = fmaf(w, v1.z, a[6]); a[7] = fmaf(w, v1.w, a[7]);
    }
  }
  int j0 = t * 4;
  atomicAdd(&c[j0 + 0], a[0]); atomicAdd(&c[j0 + 1], a[1]);
  atomicAdd(&c[j0 + 2], a[2]); atomicAdd(&c[j0 + 3], a[3]);
  atomicAdd(&c[1024 + j0 + 0], a[4]); atomicAdd(&c[1024 + j0 + 1], a[5]);
  atomicAdd(&c[1024 + j0 + 2], a[6]); atomicAdd(&c[1024 + j0 + 3], a[7]);
}

// ---------------------------------------------------------------------------
// K4: hr[n] += (c/Z) . W_r1[:,n]
// ---------------------------------------------------------------------------
__global__ __launch_bounds__(256) void r1_kernel(
    const float* __restrict__ c, const float* __restrict__ Z,
    const float* __restrict__ cnt, const float* __restrict__ Wr1,
    float* __restrict__ hr)
{
  __shared__ float cs[128];
  int n  = blockIdx.x * 256 + threadIdx.x;
  int k0 = blockIdx.y * 128;
  float inv = (cnt[0] > 0.5f) ? (1.f / Z[0]) : 0.f;
  if (threadIdx.x < 128) cs[threadIdx.x] = c[k0 + threadIdx.x] * inv;
  __syncthreads();
  float s = 0.f;
#pragma unroll 8
  for (int k = 0; k < 128; k++)
    s = fmaf(cs[k], Wr1[(size_t)(k0 + k) * HH + n], s);
  atomicAdd(&hr[n], s);
}

// ---------------------------------------------------------------------------
// K5: rt[n] += relu(hr + b_r1) . W_r2[:,n]
// ---------------------------------------------------------------------------
__global__ __launch_bounds__(256) void r2_kernel(
    const float* __restrict__ hr, const float* __restrict__ br1,
    const float* __restrict__ Wr2, float* __restrict__ rt)
{
  __shared__ float hs[128];
  int n  = blockIdx.x * 256 + threadIdx.x;
  int k0 = blockIdx.y * 128;
  if (threadIdx.x < 128)
    hs[threadIdx.x] = fmaxf(hr[k0 + threadIdx.x] + br1[k0 + threadIdx.x], 0.f);
  __syncthreads();
  float s = 0.f;
#pragma unroll 8
  for (int k = 0; k < 128; k++)
    s = fmaf(hs[k], Wr2[(size_t)(k0 + k) * H_ + n], s);
  atomicAdd(&rt[n], s);
}

// ---------------------------------------------------------------------------
// K6: add[j] = has_events ? sigmoid(rt[j] + b_r2[j]) : 0
// ---------------------------------------------------------------------------
__global__ __launch_bounds__(256) void finalize_kernel(
    const float* __restrict__ rt, const float* __restrict__ br2,
    const float* __restrict__ cnt, float* __restrict__ addv)
{
  int j = blockIdx.x * 256 + threadIdx.x;
  float v = 0.f;
  if (cnt[0] > 0.5f) v = 1.f / (1.f + expf(-(rt[j] + br2[j])));
  addv[j] = v;
}

// ---------------------------------------------------------------------------
// K7: out = x + add (broadcast over rows)
// ---------------------------------------------------------------------------
__global__ __launch_bounds__(256) void out_kernel(
    const float* __restrict__ x, const float* __restrict__ addv,
    float* __restrict__ out)
{
  size_t i = (size_t)blockIdx.x * 256 + threadIdx.x;
  int j4 = (int)(i & 511);
  float4 a = reinterpret_cast<const float4*>(addv)[j4];
  float4 v = reinterpret_cast<const float4*>(x)[i];
  v.x += a.x; v.y += a.y; v.z += a.z; v.w += a.w;
  reinterpret_cast<float4*>(out)[i] = v;
}

// ---------------------------------------------------------------------------
extern "C" void kernel_launch(void* const* d_in, const int* in_sizes, int n_in,
                              void* d_out, int out_size, void* d_ws, size_t ws_size,
                              hipStream_t stream)
{
  (void)in_sizes; (void)n_in; (void)out_size;
  const float* x   = (const float*)d_in[0];
  const float* imp = (const float*)d_in[1];
  const float* We1 = (const float*)d_in[2];
  const float* be1 = (const float*)d_in[3];
  const float* We2 = (const float*)d_in[4];
  const float* be2 = (const float*)d_in[5];
  const float* Wr1 = (const float*)d_in[6];
  const float* br1 = (const float*)d_in[7];
  const float* Wr2 = (const float*)d_in[8];
  const float* br2 = (const float*)d_in[9];
  float* out = (float*)d_out;

  float* ws    = (float*)d_ws;
  float* s_pre = ws;            // 16384
  float* c     = ws + 16384;    // 2048
  float* hr    = ws + 18432;    // 1024
  float* rt    = ws + 19456;    // 2048
  float* Z     = ws + 21504;    // 1
  float* cnt   = ws + 21505;    // 1
  float* wbuf  = ws + 21760;    // 16384 (fully written, no init)
  float* addv  = ws + 38144;    // 2048  (fully written, no init)

  const size_t scal_bytes = 49152 * sizeof(float);             // 196608 B
  const size_t xb_bytes   = (size_t)NROWS * H_ * 2;            // 67.1 MB
  const size_t w1t_bytes  = (size_t)HH * H_ * 2;               // 4.2 MB
  unsigned short* xb  = (unsigned short*)((char*)d_ws + scal_bytes);
  unsigned short* W1t = (unsigned short*)((char*)d_ws + scal_bytes + xb_bytes);
  const bool fast = ws_size >= scal_bytes + xb_bytes + w1t_bytes;

  hipMemsetAsync(d_ws, 0, 21506 * sizeof(float), stream);

  if (fast) {
    convert_x_kernel<<<16384, 256, 0, stream>>>(x, xb);
    transpose_w1_kernel<<<dim3(32, 16), 256, 0, stream>>>(We1, W1t);
    gemm_v2_kernel<<<dim3(8, 128), 256, 0, stream>>>(xb, W1t, be1, We2, s_pre);
  } else {
    gemm_score_kernel<<<dim3(8, 128), 256, 0, stream>>>(x, We1, be1, We2, s_pre);
  }
  score_kernel<<<64, 256, 0, stream>>>(s_pre, imp, be2, wbuf, Z, cnt);
  consolidate_kernel<<<128, 256, 0, stream>>>(x, wbuf, c);
  r1_kernel<<<dim3(4, 16), 256, 0, stream>>>(c, Z, cnt, Wr1, hr);
  r2_kernel<<<dim3(8, 8), 256, 0, stream>>>(hr, br1, Wr2, rt);
  finalize_kernel<<<8, 256, 0, stream>>>(rt, br2, cnt, addv);
  out_kernel<<<32768, 256, 0, stream>>>(x, addv, out);
}